// Round 8
// baseline (75.126 us; speedup 1.0000x reference)
//
#include <hip/hip_runtime.h>
#include <hip/hip_bf16.h>
#include <math.h>

// KL PowerSpherical contrastive loss via deterministic quadrature +
// per-column Chebyshev interpolation. All-float, hardware transcendentals.
// Two dispatches total; final reduction via per-block atomicAdd.
//
//   sim[i,j] = 0.1 * scale_j * ( ln2 + psi(a_j) - psi(a_j+b) - F_j(c_ij) )
//   F_j(c)   = E_{t,u}[ log1p(t*c + sqrt(1-t^2)*sqrt(1-c^2)*u) ]
//   c_ij     = loc_i . loc_j
// Quadrature: 16 t-nodes (midpoint over +-8 sigma of Beta marginal, weights
// normalized) x 16 u-nodes (midpoint, weight (1-u^2)^62 normalized).
// F_j interpolated by degree-15 Chebyshev; errors ~1e-5/entry vs 0.1275 budget.

#define NJ 512
#define NT 16
#define NU 16
#define NC 16

__device__ __forceinline__ float digf(float x) {
    float r  = __frcp_rn(x);
    float r2 = r * r;
    return __logf(x) - 0.5f * r - r2 * (1.0f/12.0f - r2 * (1.0f/120.0f));
}

// ---- kernel A: per-column quadrature + Cheb coeffs + loc transpose -------
// one block (4 waves) per column j; wave 1 also scatters loc_j into locT4;
// block 0 zeroes d_out for kernel B's atomics.
__global__ __launch_bounds__(256)
void fcoef_kernel(const float* __restrict__ loc1, const float* __restrict__ loc2,
                  const float* __restrict__ s1, const float* __restrict__ s2,
                  float4* __restrict__ locT4, float* __restrict__ coefT,
                  float2* __restrict__ jc, float* __restrict__ out) {
    const int j    = blockIdx.x;
    const int tid  = threadIdx.x;
    const int lane = tid & 63;
    const int wave = tid >> 6;

    __shared__ float t_s[NT], st_s[NT], w_s[NT];
    __shared__ float Fv[NC];

    if (j == 0 && tid == 0) out[0] = 0.0f;   // stream-ordered before kernel B

    if (wave == 0) {
        float scale = (j < 256) ? s1[j] : s2[j - 256];
        float a = 63.5f + scale, b = 63.5f, apb = a + b;
        float K = 0.69314718056f + digf(a) - digf(apb);
        float mu  = a / apb;
        float sig = sqrtf(a * b / (apb * apb * (apb + 1.0f)));
        float zlo = fmaxf(mu - 8.0f * sig, 1e-7f);
        float zhi = fminf(mu + 8.0f * sig, 1.0f - 1e-7f);
        float h   = (zhi - zlo) / (float)NT;

        int   k  = lane & 15;
        float z  = zlo + ((float)k + 0.5f) * h;
        float lw = (a - 1.0f) * __logf(z) + (b - 1.0f) * log1pf(-z);
        float mxl = lw;
        #pragma unroll
        for (int m = 8; m >= 1; m >>= 1) mxl = fmaxf(mxl, __shfl_xor(mxl, m));
        float w  = __expf(lw - mxl);
        float ws = w;
        #pragma unroll
        for (int m = 8; m >= 1; m >>= 1) ws += __shfl_xor(ws, m);
        w /= ws;
        float t = 2.0f * z - 1.0f;
        if (lane < 16) {
            t_s[k]  = t;
            st_s[k] = sqrtf(fmaxf(0.0f, 1.0f - t * t));
            w_s[k]  = w;
        }
        if (lane == 0) jc[j] = make_float2(K, 0.1f * scale);
    } else if (wave == 1 && lane < 32) {
        // transpose: locT4[g*512 + j] = float4 g of loc row j
        const float* lj = (j < 256) ? (loc1 + j * 128) : (loc2 + (j - 256) * 128);
        locT4[lane * NJ + j] = ((const float4*)lj)[lane];
    }
    __syncthreads();

    // u-grid: midpoint on [-0.72, 0.72], weight (1-u^2)^62, normalized
    const float UMAX = 0.72f;
    const float hu   = (2.0f * UMAX) / (float)NU;
    int   uu = lane & 15;
    float u  = -UMAX + ((float)uu + 0.5f) * hu;
    float wu = __expf(62.0f * log1pf(-u * u));
    float wus = wu;
    #pragma unroll
    for (int m = 8; m >= 1; m >>= 1) wus += __shfl_xor(wus, m);
    wu /= wus;

    const int t0 = lane >> 4;   // 0..3
    for (int node = wave; node < NC; node += 4) {
        float c  = __cosf((float)M_PI * ((float)node + 0.5f) / (float)NC);
        float sC = sqrtf(fmaxf(0.0f, 1.0f - c * c));
        float su = sC * u;
        float acc = 0.0f;
        #pragma unroll
        for (int r = 0; r < 4; r++) {
            int   tt = t0 + 4 * r;
            float mm = fmaf(st_s[tt], su, t_s[tt] * c);
            acc = fmaf(w_s[tt] * wu, __logf(1.0f + mm), acc);
        }
        #pragma unroll
        for (int m = 32; m >= 1; m >>= 1) acc += __shfl_xor(acc, m);
        if (lane == 0) Fv[node] = acc;
    }
    __syncthreads();

    if (tid < NC) {
        float s = 0.0f;
        #pragma unroll
        for (int k = 0; k < NC; k++)
            s += Fv[k] * __cosf((float)M_PI * (float)tid * ((float)k + 0.5f) / (float)NC);
        coefT[tid * NJ + j] = s * (tid == 0 ? 1.0f / (float)NC : 2.0f / (float)NC);
    }
}

// ---- kernel B: 512x512 sim + row logsumexp + atomic mean -----------------
__global__ __launch_bounds__(512)
void sim2_kernel(const float4* __restrict__ locT4,
                 const float* __restrict__ loc1, const float* __restrict__ loc2,
                 const float* __restrict__ coefT, const float2* __restrict__ jc,
                 float* __restrict__ out) {
    const int i = blockIdx.x;
    const int j = threadIdx.x;
    __shared__ float4 li4[32];
    __shared__ float wmx[8], wsm[8], posv;

    const float* li = (i < 256) ? (loc1 + i * 128) : (loc2 + (i - 256) * 128);
    if (j < 32) li4[j] = ((const float4*)li)[j];
    __syncthreads();

    float c = 0.0f;
    #pragma unroll
    for (int g = 0; g < 32; g++) {
        float4 v = locT4[g * NJ + j];
        float4 a = li4[g];
        c = fmaf(v.x, a.x, fmaf(v.y, a.y, fmaf(v.z, a.z, fmaf(v.w, a.w, c))));
    }
    c = fminf(1.0f, fmaxf(-1.0f, c));

    // Clenshaw
    float b1 = 0.0f, b2 = 0.0f;
    const float tc = 2.0f * c;
    #pragma unroll
    for (int m = NC - 1; m >= 1; m--) {
        float bn = fmaf(tc, b1, coefT[m * NJ + j] - b2);
        b2 = b1; b1 = bn;
    }
    float F = fmaf(c, b1, coefT[j] - b2);

    float2 kg  = jc[j];
    float  sim = kg.y * (kg.x - F);
    if (j == i) sim = -3.0e38f;
    if (j == (i ^ 256)) posv = sim;

    float mx = sim;
    #pragma unroll
    for (int m = 32; m >= 1; m >>= 1) mx = fmaxf(mx, __shfl_xor(mx, m));
    int lane = j & 63, wave = j >> 6;
    if (lane == 0) wmx[wave] = mx;
    __syncthreads();
    float M = wmx[0];
    #pragma unroll
    for (int w = 1; w < 8; w++) M = fmaxf(M, wmx[w]);

    float e = __expf(sim - M);      // diagonal underflows to 0
    #pragma unroll
    for (int m = 32; m >= 1; m >>= 1) e += __shfl_xor(e, m);
    if (lane == 0) wsm[wave] = e;
    __syncthreads();
    if (j == 0) {
        float S = 0.0f;
        #pragma unroll
        for (int w = 0; w < 8; w++) S += wsm[w];
        atomicAdd(out, (posv - (M + __logf(S))) * (1.0f / 512.0f));
    }
}

extern "C" void kernel_launch(void* const* d_in, const int* in_sizes, int n_in,
                              void* d_out, int out_size, void* d_ws, size_t ws_size,
                              hipStream_t stream) {
    const float* loc1 = (const float*)d_in[0];
    const float* s1   = (const float*)d_in[1];
    const float* loc2 = (const float*)d_in[2];
    const float* s2   = (const float*)d_in[3];
    float* out = (float*)d_out;

    char* ws = (char*)d_ws;
    float4* locT4 = (float4*)(ws);                 // 262144 B
    float*  coefT = (float*) (ws + 262144);        //  32768 B (16*512*4)
    float2* jc    = (float2*)(ws + 294912);        //   4096 B

    fcoef_kernel<<<NJ, 256, 0, stream>>>(loc1, loc2, s1, s2, locT4, coefT, jc, out);
    sim2_kernel <<<NJ, 512, 0, stream>>>(locT4, loc1, loc2, coefT, jc, out);
}